// Round 1
// 373.714 us; speedup vs baseline: 1.1098x; 1.1098x over previous
//
#include <hip/hip_runtime.h>
#include <math.h>

#define BG   128            // graphs
#define NPER 1024           // nodes per graph, level 0
#define HDIM 128            // hidden
#define NEDGE (BG * NPER * 8)
#define NMAX (BG * NPER)    // 131072
#define EPG  (NEDGE / BG)   // 8192 edges per graph (contiguous slice!)
#define CAP  48             // per-node edge capacity (Poisson(8) tail ~1e-15)
#define PRE  16             // packed-meta entries per node (P(deg>16) ~ 0.4%)
#define CROWS 64            // conv tile rows

typedef __attribute__((ext_vector_type(8))) short s16x8;   // 8 bf16 (4 VGPRs)
typedef __attribute__((ext_vector_type(4))) float f32x4;   // MFMA C/D

static __device__ __forceinline__ ushort f2bf(float f) {   // RNE f32 -> bf16
  uint u = __float_as_uint(f);
  return (ushort)((u + 0x7fffu + ((u >> 16) & 1u)) >> 16);
}
static __device__ __forceinline__ float bf2f(ushort h) {
  return __uint_as_float(((uint)h) << 16);
}

// ---------------------------------------------------------------------------
// L0 merged count+fill: ONE atomic per edge gives both the slot position and
// (at the end) the degree. Edge coefficients no longer exist — the GCN norm
// is factored as z[c] = dinv[c] * (sum_e xs[src] + xs[c]) with xs = x*dinv,
// so meta holds ONLY graph-local src ids (int, half the old int2 traffic).
// ---------------------------------------------------------------------------

__global__ __launch_bounds__(256) void countfill_kernel(
    const int* __restrict__ cr, const int* __restrict__ cc,
    int* __restrict__ cnt, int* __restrict__ meta8,
    int* __restrict__ srcext, int mask) {
  int e = blockIdx.x * 256 + threadIdx.x;
  int c = cc[e];
  int rl = cr[e] & mask;                       // graph-local row index
  int pos = atomicAdd(&cnt[c], 1);
  if (pos < PRE) {
    meta8[(size_t)c * PRE + pos] = rl;
  } else if (pos < CAP) {
    srcext[(size_t)c * CAP + pos] = rl;
  }
}

extern __shared__ float ldsbuf[];

// ---------------------------------------------------------------------------
// LDS-resident aggregation (round-16 shape, simplified math):
//  block = (graph, 32-ch chunk); stage PRE-SCALED rows xs = x*dinv -> LDS,
//  one barrier, then each 8-lane group walks its dsts: meta = coalesced int2
//  (2 src ids) + __shfl broadcast; per edge ONE ds_read_b128 + 4 adds (no
//  coefficient!); final multiply by dinv[dst].
// ---------------------------------------------------------------------------

__global__ __launch_bounds__(1024) void agg_lds_kernel(
    const float* __restrict__ x, float* __restrict__ z,
    const int* __restrict__ meta8, const int* __restrict__ srcext,
    const int* __restrict__ deg, int npg) {
  float* sX = ldsbuf;                          // [npg][32], pre-scaled
  float* sDinv = sX + npg * 32;                // [npg]
  int g = blockIdx.x >> 2;
  int chunk = blockIdx.x & 3;
  int t = threadIdx.x;
  int base = g * npg;

  const float4* x4 = (const float4*)x;
  float4* sX4 = (float4*)sX;
  for (int i = t; i < npg * 8; i += 1024) {
    int r = i >> 3, l8 = i & 7;
    float dv = rsqrtf((float)deg[base + r] + 1.0f);
    float4 v = x4[(size_t)(base + r) * 32 + chunk * 8 + l8];
    v.x *= dv; v.y *= dv; v.z *= dv; v.w *= dv;
    sX4[i] = v;
  }
  for (int i = t; i < npg; i += 1024)
    sDinv[i] = rsqrtf((float)deg[base + i] + 1.0f);
  __syncthreads();

  int dl = t >> 3, l = t & 7;                  // dst-local slot, lane 0..7
  int base8 = (t & 63) & 56;                   // 8-lane group base within wave
  const int2* m2 = (const int2*)meta8;
  for (int dst = dl; dst < npg; dst += 128) {
    int node = base + dst;
    int2 mq = m2[(size_t)node * 8 + l];        // src ids for edges 2l, 2l+1
    int d = deg[node];
    if (d > CAP) d = CAP;
    float dc = sDinv[dst];
    float4 a0 = sX4[dst * 8 + l];              // self term (xs[c]); *dc later
    float4 a1 = make_float4(0.f, 0.f, 0.f, 0.f);
    int dp = d < PRE ? d : PRE;
    int e = 0;
    for (; e + 1 < dp; e += 2) {
      int sl = base8 + (e >> 1);
      int si0 = __shfl(mq.x, sl);
      int si1 = __shfl(mq.y, sl);
      float4 v0 = sX4[si0 * 8 + l];
      float4 v1 = sX4[si1 * 8 + l];
      a0.x += v0.x; a0.y += v0.y; a0.z += v0.z; a0.w += v0.w;
      a1.x += v1.x; a1.y += v1.y; a1.z += v1.z; a1.w += v1.w;
    }
    if (e < dp) {
      int sl = base8 + (e >> 1);
      int si0 = __shfl(mq.x, sl);
      float4 v0 = sX4[si0 * 8 + l];
      a0.x += v0.x; a0.y += v0.y; a0.z += v0.z; a0.w += v0.w;
    }
    for (int e2 = PRE; e2 < d; ++e2) {         // rare overflow (deg > 16)
      int rl = srcext[(size_t)node * CAP + e2];
      float4 v0 = sX4[rl * 8 + l];
      a0.x += v0.x; a0.y += v0.y; a0.z += v0.z; a0.w += v0.w;
    }
    float4 o = make_float4((a0.x + a1.x) * dc, (a0.y + a1.y) * dc,
                           (a0.z + a1.z) * dc, (a0.w + a1.w) * dc);
    ((float4*)z)[(size_t)node * 32 + chunk * 8 + l] = o;
  }
}

// ---------------------------------------------------------------------------
// W prep: 3-way bf16 split (hi/mid/lo, residual <= 2^-27 rel) of each level's
// W, packed directly in MFMA B-fragment order for 16x16x32_bf16:
//   B[k][n]: lane l holds k = kt*32 + (l>>4)*8 + i, n = nt*16 + (l&15)
//   layout: [L][split][kt][nt][lane][i]  (each fragment = 16 B contiguous)
// Runs once; 3*3*32 KB total.
// ---------------------------------------------------------------------------

__global__ __launch_bounds__(256) void wsplit_kernel(
    const float* __restrict__ W0, const float* __restrict__ W1,
    const float* __restrict__ W2, ushort* __restrict__ wpk) {
  int id = blockIdx.x * 256 + threadIdx.x;     // 3*16384 total
  int L = id >> 14;
  int r = id & 16383;                          // ((kt*8+nt)*64+lane)*8+i
  int i = r & 7;
  int lane = (r >> 3) & 63;
  int nt = (r >> 9) & 7;
  int kt = (r >> 12) & 3;
  int k = kt * 32 + (lane >> 4) * 8 + i;
  int n = nt * 16 + (lane & 15);
  const float* W = (L == 0) ? W0 : (L == 1) ? W1 : W2;
  float v = W[k * HDIM + n];
  ushort h = f2bf(v);
  float r1 = v - bf2f(h);
  ushort m = f2bf(r1);
  ushort lo = f2bf(r1 - bf2f(m));
  size_t base = (size_t)L * 3 * 16384 + (size_t)r;
  wpk[base] = h;
  wpk[base + 16384] = m;
  wpk[base + 32768] = lo;
}

// ---------------------------------------------------------------------------
// conv via MFMA split-precision: h = relu(z @ W + b) in-place; score = h . p.
// Each wave owns 16 rows (4 waves = 64 rows/block). fp32 z is 3-way bf16
// split in registers; 6 product terms (hh,hm,mh,hl,lh,mm) per K-tile keep
// error ~2^-27 rel (fp32-rounding level -> topk ordering preserved).
// B-fragments: coalesced 16 B/lane dwordx4 from pre-packed wpk (L2-hot).
// No LDS, no barriers. 192 MFMAs/wave; dispatch is memory-bound on z/h.
// ---------------------------------------------------------------------------

__global__ __launch_bounds__(256) void conv_mfma_kernel(
    float* __restrict__ zh, const ushort* __restrict__ wpk,
    const float* __restrict__ bias, const float* __restrict__ p,
    float* __restrict__ score) {
  int t = threadIdx.x;
  int wv = t >> 6, l = t & 63;
  int lr = l & 15, lq = l >> 4;                // A-row in tile, quarter
  int arow = blockIdx.x * CROWS + wv * 16 + lr;
  const float* zrow = zh + (size_t)arow * HDIM + lq * 8;

  // ---- load + 3-way split A fragments (k = kt*32 + lq*8 + i) ----
  s16x8 ah[4], am[4], al[4];
  #pragma unroll
  for (int kt = 0; kt < 4; ++kt) {
    float4 v0 = ((const float4*)(zrow + kt * 32))[0];
    float4 v1 = ((const float4*)(zrow + kt * 32))[1];
    float f[8] = {v0.x, v0.y, v0.z, v0.w, v1.x, v1.y, v1.z, v1.w};
    #pragma unroll
    for (int i = 0; i < 8; ++i) {
      ushort h = f2bf(f[i]);
      float r1 = f[i] - bf2f(h);
      ushort m = f2bf(r1);
      ushort lo = f2bf(r1 - bf2f(m));
      ah[kt][i] = (short)h; am[kt][i] = (short)m; al[kt][i] = (short)lo;
    }
  }

  f32x4 acc[8];
  #pragma unroll
  for (int nt = 0; nt < 8; ++nt) acc[nt] = (f32x4)(0.f);

  const s16x8* wh = (const s16x8*)wpk;         // fragment-granular views
  const s16x8* wm = wh + 2048;
  const s16x8* wl = wm + 2048;

  #pragma unroll
  for (int kt = 0; kt < 4; ++kt) {
    #pragma unroll
    for (int nt = 0; nt < 8; ++nt) {
      int fi = (kt * 8 + nt) * 64 + l;
      s16x8 bh = wh[fi];
      s16x8 bm = wm[fi];
      s16x8 bl = wl[fi];
      acc[nt] = __builtin_amdgcn_mfma_f32_16x16x32_bf16(ah[kt], bh, acc[nt], 0, 0, 0);
      acc[nt] = __builtin_amdgcn_mfma_f32_16x16x32_bf16(ah[kt], bm, acc[nt], 0, 0, 0);
      acc[nt] = __builtin_amdgcn_mfma_f32_16x16x32_bf16(am[kt], bh, acc[nt], 0, 0, 0);
      acc[nt] = __builtin_amdgcn_mfma_f32_16x16x32_bf16(ah[kt], bl, acc[nt], 0, 0, 0);
      acc[nt] = __builtin_amdgcn_mfma_f32_16x16x32_bf16(al[kt], bh, acc[nt], 0, 0, 0);
      acc[nt] = __builtin_amdgcn_mfma_f32_16x16x32_bf16(am[kt], bm, acc[nt], 0, 0, 0);
    }
  }

  // ---- epilogue: bias + relu + score + in-place store ----
  // C/D layout (m89-verified): row = lq*4 + j, col = nt*16 + lr
  int orow = blockIdx.x * CROWS + wv * 16 + lq * 4;
  float part[4] = {0.f, 0.f, 0.f, 0.f};
  #pragma unroll
  for (int nt = 0; nt < 8; ++nt) {
    float bv = bias[nt * 16 + lr];
    float pv = p[nt * 16 + lr];
    #pragma unroll
    for (int j = 0; j < 4; ++j) {
      float hv = fmaxf(acc[nt][j] + bv, 0.f);
      part[j] += hv * pv;
      zh[(size_t)(orow + j) * HDIM + nt * 16 + lr] = hv;
    }
  }
  #pragma unroll
  for (int j = 0; j < 4; ++j) {
    #pragma unroll
    for (int s = 1; s < 16; s <<= 1) part[j] += __shfl_xor(part[j], s);
    if (lr == 0) score[orow + j] = part[j];
  }
}

// ---------------------------------------------------------------------------
// MEGA: per-graph block (P threads) — sort + pool/readout + relabel + next-
// layer count/fill via LDS. Coefficient-free meta: relabel loop writes meta8
// directly with ONE LDS atomic (slot+count combined); no second fill pass,
// no barrier between count and fill. L==2 also emits the final output.
// ---------------------------------------------------------------------------

__global__ __launch_bounds__(1024) void topk_mega_kernel(
    const float* __restrict__ score, const float* __restrict__ p,
    const float* __restrict__ h, float* __restrict__ xo,
    const int* __restrict__ in_r, const int* __restrict__ in_c,
    int* __restrict__ out_r, int* __restrict__ out_c,
    int* __restrict__ meta8, int* __restrict__ srcext,
    int* __restrict__ cnt, float* __restrict__ acc,
    float* __restrict__ outf, int P, int K, int L) {
  __shared__ float sv[1024];
  __shared__ int si[1024];
  __shared__ int snew[1024];
  __shared__ int scnt[512];
  __shared__ float s_pn;
  __shared__ float4 smx[32][32], ssm[32][32];
  int g = blockIdx.x;
  int t = threadIdx.x;

  if (L < 2 && t < 512) scnt[t] = 0;
  snew[t] = -1;
  if (t < 128) { float v = p[t]; sv[t] = v * v; }
  __syncthreads();
  for (int off = 64; off; off >>= 1) {
    if (t < off) sv[t] += sv[t + off];
    __syncthreads();
  }
  if (t == 0) s_pn = sqrtf(sv[0]);
  __syncthreads();
  float pn = s_pn;

  sv[t] = score[(size_t)g * P + t];
  si[t] = t;
  for (int size = 2; size <= P; size <<= 1) {
    for (int stride = size >> 1; stride; stride >>= 1) {
      __syncthreads();
      int j = t ^ stride;
      if (j > t) {
        float a = sv[t], b = sv[j];
        int ia = si[t], ib = si[j];
        bool tFirst = (a > b) || (a == b && ia < ib);
        bool up = ((t & size) == 0);
        if (up ? !tFirst : tFirst) {
          sv[t] = b; sv[j] = a;
          si[t] = ib; si[j] = ia;
        }
      }
    }
  }
  __syncthreads();
  if (t < K) {
    snew[si[t]] = t;                           // graph-LOCAL new id
    sv[t] = tanhf(sv[t] / pn);                 // sv now holds the scale
  }
  __syncthreads();

  // ---- gather + readout: group = 32 lanes, 16 rows per group ----
  int lane = t & 31, grp = t >> 5;             // ngrp = P/32; K/ngrp == 16
  const float4* h4 = (const float4*)h;
  float4* xo4 = (float4*)xo;
  size_t hbase = (size_t)g * P * 32;
  float4 mx = make_float4(-INFINITY, -INFINITY, -INFINITY, -INFINITY);
  float4 sm = make_float4(0.f, 0.f, 0.f, 0.f);
  #pragma unroll
  for (int i = 0; i < 16; ++i) {
    int j = grp * 16 + i;
    float th = sv[j];
    float4 v = h4[hbase + (size_t)si[j] * 32 + lane];
    v.x *= th; v.y *= th; v.z *= th; v.w *= th;
    xo4[((size_t)g * K + j) * 32 + lane] = v;
    mx.x = fmaxf(mx.x, v.x); mx.y = fmaxf(mx.y, v.y);
    mx.z = fmaxf(mx.z, v.z); mx.w = fmaxf(mx.w, v.w);
    sm.x += v.x; sm.y += v.y; sm.z += v.z; sm.w += v.w;
  }
  smx[grp][lane] = mx;
  ssm[grp][lane] = sm;
  __syncthreads();
  int ngrp = P >> 5;
  if (grp == 0) {
    for (int s2 = 1; s2 < ngrp; ++s2) {
      float4 m2 = smx[s2][lane], s3 = ssm[s2][lane];
      mx.x = fmaxf(mx.x, m2.x); mx.y = fmaxf(mx.y, m2.y);
      mx.z = fmaxf(mx.z, m2.z); mx.w = fmaxf(mx.w, m2.w);
      sm.x += s3.x; sm.y += s3.y; sm.z += s3.z; sm.w += s3.w;
    }
    int c0 = lane * 4;
    if (L < 2) {
      float* amax = acc + (size_t)L * BG * 256 + (size_t)g * 256;
      float* asum = amax + 128;
      amax[c0 + 0] = mx.x; amax[c0 + 1] = mx.y;
      amax[c0 + 2] = mx.z; amax[c0 + 3] = mx.w;
      asum[c0 + 0] = sm.x; asum[c0 + 1] = sm.y;
      asum[c0 + 2] = sm.z; asum[c0 + 3] = sm.w;
    } else {                                   // stash own readout in sv
      sv[c0 + 0] = mx.x; sv[c0 + 1] = mx.y;
      sv[c0 + 2] = mx.z; sv[c0 + 3] = mx.w;
      sv[128 + c0 + 0] = sm.x; sv[128 + c0 + 1] = sm.y;
      sv[128 + c0 + 2] = sm.z; sv[128 + c0 + 3] = sm.w;
    }
  }

  if (L == 2) {                                // fold final combine in
    __syncthreads();
    float v;
    const float* a0 = acc + (size_t)g * 256;
    const float* a1 = acc + (size_t)BG * 256 + (size_t)g * 256;
    if (t < 128) {
      v = a0[t] + a1[t] + sv[t];
    } else {
      v = a0[t] * (1.f / 512.f) + a1[t] * (1.f / 256.f) + sv[t] * (1.f / 128.f);
    }
    outf[g * 256 + t] = v;
    return;
  }

  // ---- relabel + count + fill in ONE pass (single LDS atomic per edge) ----
  int ept = EPG / P;                           // 8 (P=1024) or 16 (P=512)
  int ebase = g * EPG;
  for (int i = 0; i < ept; ++i) {
    int e = ebase + i * P + t;                 // coalesced
    int r = in_r[e];
    int nr = -1, nc = -1;
    if (r >= 0) {
      nr = snew[r & (P - 1)];
      nc = snew[in_c[e] & (P - 1)];
    }
    bool ok = (nr >= 0) && (nc >= 0);
    out_r[e] = ok ? g * K + nr : -1;
    out_c[e] = ok ? g * K + nc : -1;
    if (ok) {
      int pos = atomicAdd(&scnt[nc], 1);
      size_t gnode = (size_t)g * K + nc;
      if (pos < PRE) {
        meta8[gnode * PRE + pos] = nr;
      } else if (pos < CAP) {
        srcext[gnode * CAP + pos] = nr;
      }
    }
  }
  __syncthreads();                             // scnt complete
  if (t < K) cnt[g * K + t] = scnt[t];         // deg for next agg (coalesced)
}

// ---------------------------------------------------------------------------
// launch
// ---------------------------------------------------------------------------

extern "C" void kernel_launch(void* const* d_in, const int* in_sizes, int n_in,
                              void* d_out, int out_size, void* d_ws, size_t ws_size,
                              hipStream_t stream) {
  const float* x0 = (const float*)d_in[0];
  const int* erow = (const int*)d_in[1];
  const int* ecol = (const int*)d_in[2];
  const float* Wm[3] = {(const float*)d_in[3], (const float*)d_in[6], (const float*)d_in[9]};
  const float* bm[3] = {(const float*)d_in[4], (const float*)d_in[7], (const float*)d_in[10]};
  const float* pm[3] = {(const float*)d_in[5], (const float*)d_in[8], (const float*)d_in[11]};

  char* w = (char*)d_ws;
  size_t off = 0;
  auto alloc = [&](size_t bytes) -> void* {
    void* ptr = w + off;
    off = (off + bytes + 255) & ~(size_t)255;
    return ptr;
  };
  int* cur_row = (int*)alloc((size_t)NEDGE * 4);
  int* cur_col = (int*)alloc((size_t)NEDGE * 4);
  int* meta8   = (int*)alloc((size_t)NMAX * PRE * 4);
  int* srcext  = (int*)alloc((size_t)NMAX * CAP * 4);
  int* cnt     = (int*)alloc((size_t)NMAX * 4);
  float* score = (float*)alloc((size_t)NMAX * 4);
  float* acc   = (float*)alloc((size_t)2 * BG * 256 * 4);
  float* zh    = (float*)alloc((size_t)NMAX * HDIM * 4);
  float* x1    = (float*)alloc((size_t)BG * 512 * HDIM * 4);
  float* x2    = (float*)alloc((size_t)BG * 256 * HDIM * 4);
  float* x3    = (float*)alloc((size_t)BG * 128 * HDIM * 4);
  ushort* wpk  = (ushort*)alloc((size_t)3 * 3 * 16384 * 2);  // packed W splits

  // allow >64 KB dynamic LDS for the agg kernel (L0 needs 132 KB)
  hipFuncSetAttribute((const void*)agg_lds_kernel,
                      hipFuncAttributeMaxDynamicSharedMemorySize, 152 * 1024);

  hipMemsetAsync(cnt, 0, (size_t)NMAX * 4, stream);
  countfill_kernel<<<NEDGE / 256, 256, 0, stream>>>(erow, ecol, cnt, meta8,
                                                    srcext, NPER - 1);
  wsplit_kernel<<<(3 * 16384) / 256, 256, 0, stream>>>(Wm[0], Wm[1], Wm[2], wpk);

  const float* xin = x0;
  float* xout[3] = {x1, x2, x3};
  int Ps[3] = {1024, 512, 256};

  for (int L = 0; L < 3; ++L) {
    int P = Ps[L];
    int K = P >> 1;
    int n = BG * P;
    const int* in_r = (L == 0) ? erow : cur_row;
    const int* in_c = (L == 0) ? ecol : cur_col;
    size_t ldsBytes = (size_t)(P * 33) * 4;

    agg_lds_kernel<<<BG * 4, 1024, ldsBytes, stream>>>(
        xin, zh, meta8, srcext, cnt, P);
    conv_mfma_kernel<<<n / CROWS, 256, 0, stream>>>(
        zh, wpk + (size_t)L * 3 * 16384, bm[L], pm[L], score);
    topk_mega_kernel<<<BG, P, 0, stream>>>(
        score, pm[L], zh, xout[L], in_r, in_c, cur_row, cur_col,
        meta8, srcext, cnt, acc, (float*)d_out, P, K, L);
    xin = xout[L];
  }
}